// Round 15
// baseline (186.393 us; speedup 1.0000x reference)
//
#include <hip/hip_runtime.h>

// GCN decoder: 2x GCNConv (self-loops, symmetric norm) + FC to 1024.
// n = 50000 nodes, E = 800000 directed edges, feats 64 -> 64 -> 32 -> 1024.
// Round 15: agg64g2 gathers widened to uint4 (16B/lane, 8 lanes/node,
//           32 nodes/block, launch_bounds(256,4)); aggfc FC loop uses
//           f32x2 elementwise-fma (v_pk_fma_f32). Rest frozen from round 14.

#define TB 256
#define FCTB 512
#define SCHUNK 4096        // scan elements per block (1024 thr x 4)
#define FLAGB (1 << 30)    // scan "total published" flag bit

typedef __attribute__((ext_vector_type(2))) float f32x2;

// f32 -> bf16 round-to-nearest-even
__device__ __forceinline__ unsigned short f2bf(float f) {
    unsigned u = __float_as_uint(f);
    u += 0x7fffu + ((u >> 16) & 1u);
    return (unsigned short)(u >> 16);
}

// accumulate 4 bf16 (packed uint2) into float4 (widening exact)
__device__ __forceinline__ void bf4_accum(uint2 p, float4& a) {
    a.x += __uint_as_float(p.x << 16);
    a.y += __uint_as_float(p.x & 0xffff0000u);
    a.z += __uint_as_float(p.y << 16);
    a.w += __uint_as_float(p.y & 0xffff0000u);
}

// accumulate 8 bf16 (packed uint4) into two float4s
__device__ __forceinline__ void bf8_accum(uint4 p, float4& a, float4& b) {
    a.x += __uint_as_float(p.x << 16);
    a.y += __uint_as_float(p.x & 0xffff0000u);
    a.z += __uint_as_float(p.y << 16);
    a.w += __uint_as_float(p.y & 0xffff0000u);
    b.x += __uint_as_float(p.z << 16);
    b.y += __uint_as_float(p.z & 0xffff0000u);
    b.z += __uint_as_float(p.w << 16);
    b.w += __uint_as_float(p.w & 0xffff0000u);
}

// ---- utility ------------------------------------------------------------

__global__ void k_zero(int4* __restrict__ p, int n4) {
    int i = blockIdx.x * TB + threadIdx.x;
    if (i < n4) p[i] = make_int4(0, 0, 0, 0);
}

// ---- CSR build ----------------------------------------------------------

__global__ void k_hist(const int* __restrict__ dst, int* __restrict__ cnt,
                       int* __restrict__ slot, int E) {
    int e = blockIdx.x * TB + threadIdx.x;
    if (e < E) slot[e] = atomicAdd(&cnt[dst[e]], 1);
}

// Exclusive scan cnt -> off (+ fused dinv); decoupled lookback (<=13 blocks).
__global__ __launch_bounds__(1024)
void k_scanLB(const int* __restrict__ cnt, int* __restrict__ off,
              float* __restrict__ dinv, int* __restrict__ work, int n, int E) {
    __shared__ int wsum[16];
    __shared__ int pfx_s;
    int b = blockIdx.x;
    int i4 = b * SCHUNK + threadIdx.x * 4;
    int lane = threadIdx.x & 63, wid = threadIdx.x >> 6;
    int v0 = 0, v1 = 0, v2 = 0, v3 = 0;
    if (i4 + 3 < n) {
        int4 t = *(const int4*)(cnt + i4);
        v0 = t.x; v1 = t.y; v2 = t.z; v3 = t.w;
    } else {
        if (i4 < n) v0 = cnt[i4];
        if (i4 + 1 < n) v1 = cnt[i4 + 1];
        if (i4 + 2 < n) v2 = cnt[i4 + 2];
        if (i4 + 3 < n) v3 = cnt[i4 + 3];
    }
    if (i4 < n)     dinv[i4]     = rsqrtf((float)(v0 + 1));
    if (i4 + 1 < n) dinv[i4 + 1] = rsqrtf((float)(v1 + 1));
    if (i4 + 2 < n) dinv[i4 + 2] = rsqrtf((float)(v2 + 1));
    if (i4 + 3 < n) dinv[i4 + 3] = rsqrtf((float)(v3 + 1));

    int s = v0 + v1 + v2 + v3;
    int x = s;
#pragma unroll
    for (int ofs = 1; ofs < 64; ofs <<= 1) {
        int t = __shfl_up(x, ofs, 64);
        if (lane >= ofs) x += t;
    }
    if (lane == 63) wsum[wid] = x;
    __syncthreads();
    int wp = 0;
#pragma unroll
    for (int wv = 0; wv < 16; ++wv) wp += (wv < wid) ? wsum[wv] : 0;
    int excl = wp + x - s;

    if (threadIdx.x == 0) {
        int tot = 0;
#pragma unroll
        for (int wv = 0; wv < 16; ++wv) tot += wsum[wv];
        atomicOr(&work[b], tot | FLAGB);
        int pfx = 0;
        for (int j = 0; j < b; ++j) {
            int v;
            do { v = atomicOr(&work[j], 0); } while (!(v & FLAGB));
            pfx += v & (FLAGB - 1);
        }
        pfx_s = pfx;
        if (b == 0) off[n] = E;
    }
    __syncthreads();
    excl += pfx_s;
    if (i4 < n)     off[i4]     = excl;
    if (i4 + 1 < n) off[i4 + 1] = excl + v0;
    if (i4 + 2 < n) off[i4 + 2] = excl + v0 + v1;
    if (i4 + 3 < n) off[i4 + 3] = excl + v0 + v1 + v2;
}

// ---- union dispatch: CSR fill + conv1 GEMM (bf16 out) --------------------
__global__ void k_fill_gemm(const int* __restrict__ src, const int* __restrict__ dst,
                            const int* __restrict__ off, const int* __restrict__ slot,
                            int* __restrict__ eSrc, int E, int fillBlocks,
                            const float* __restrict__ X, const float* __restrict__ W,
                            const float* __restrict__ dinv,
                            unsigned short* __restrict__ Y, int n) {
    __shared__ float Ws[64 * 64];
    __shared__ float Xs[16 * 64];
    if ((int)blockIdx.x < fillBlocks) {
        int e = blockIdx.x * TB + threadIdx.x;
        if (e < E) eSrc[off[dst[e]] + slot[e]] = src[e];
        return;
    }
    int gb = blockIdx.x - fillBlocks;
    for (int i = threadIdx.x; i < 64 * 64; i += TB) Ws[i] = W[i];
    int r0 = gb * 16;
    int rows = min(16, n - r0);
    {
        const float4* Xg = (const float4*)(X + (size_t)r0 * 64);
        float4* Xs4 = (float4*)Xs;
        int tot4 = rows * 16;
        for (int i = threadIdx.x; i < tot4; i += TB) Xs4[i] = Xg[i];
    }
    __syncthreads();
    int c = threadIdx.x & 63;
    int g = threadIdx.x >> 6;  // 0..3
#pragma unroll
    for (int rr = 0; rr < 4; ++rr) {
        int rb = g + rr * 4;
        int r = r0 + rb;
        if (r >= n) break;
        const float* x = Xs + rb * 64;
        float acc = 0.f;
#pragma unroll
        for (int k = 0; k < 64; ++k) acc = fmaf(x[k], Ws[k * 64 + c], acc);
        Y[(size_t)r * 64 + c] = f2bf(acc * dinv[r]);
    }
}

// ---- fused conv1-agg + conv2-GEMM ----------------------------------------
// Phase A: 32 nodes/block, 8 lanes/node, uint4 (16B = 8 bf16) gathers,
//          4-way unroll (8 float4 accumulators) -> post-relu rows into LDS.
// Phase B: h2b[nd,c] = bf16( dinv[nd] * rows[nd] @ W2[:,c] ), W2 in LDS.
__global__ __launch_bounds__(TB, 4)
void k_agg64g2(const uint4* __restrict__ H4b, const int* __restrict__ off,
               const int* __restrict__ eSrc, const float* __restrict__ dinv,
               const float4* __restrict__ b4, const float* __restrict__ W2,
               unsigned short* __restrict__ h2b, int n) {
    __shared__ float rowsS[32 * 64];  // 8KB
    __shared__ float W2s[64 * 32];    // 8KB
    for (int i = threadIdx.x; i < 64 * 32; i += TB) W2s[i] = W2[i];
    int r0 = blockIdx.x * 32;
    int node = r0 + (threadIdx.x >> 3);
    int feat8 = threadIdx.x & 7;       // 8 bf16 per lane; row = 8 uint4
    if (node < n) {
        int j0 = off[node], j1 = off[node + 1];
        float4 l0 = make_float4(0.f, 0.f, 0.f, 0.f), h0 = l0;
        float4 l1 = l0, h1 = l0, l2 = l0, h2 = l0, l3 = l0, h3 = l0;
        int e = j0;
        for (; e + 4 <= j1; e += 4) {
            int s0 = eSrc[e], s1 = eSrc[e + 1], s2 = eSrc[e + 2], s3 = eSrc[e + 3];
            bf8_accum(H4b[(size_t)s0 * 8 + feat8], l0, h0);
            bf8_accum(H4b[(size_t)s1 * 8 + feat8], l1, h1);
            bf8_accum(H4b[(size_t)s2 * 8 + feat8], l2, h2);
            bf8_accum(H4b[(size_t)s3 * 8 + feat8], l3, h3);
        }
        for (; e < j1; ++e) bf8_accum(H4b[(size_t)eSrc[e] * 8 + feat8], l0, h0);
        bf8_accum(H4b[(size_t)node * 8 + feat8], l1, h1);  // self-loop
        float dv = dinv[node];
        float4 bb0 = b4[feat8 * 2], bb1 = b4[feat8 * 2 + 1];
        float4 ra, rb;
        ra.x = fmaxf(fmaf((l0.x + l1.x) + (l2.x + l3.x), dv, bb0.x), 0.f);
        ra.y = fmaxf(fmaf((l0.y + l1.y) + (l2.y + l3.y), dv, bb0.y), 0.f);
        ra.z = fmaxf(fmaf((l0.z + l1.z) + (l2.z + l3.z), dv, bb0.z), 0.f);
        ra.w = fmaxf(fmaf((l0.w + l1.w) + (l2.w + l3.w), dv, bb0.w), 0.f);
        rb.x = fmaxf(fmaf((h0.x + h1.x) + (h2.x + h3.x), dv, bb1.x), 0.f);
        rb.y = fmaxf(fmaf((h0.y + h1.y) + (h2.y + h3.y), dv, bb1.y), 0.f);
        rb.z = fmaxf(fmaf((h0.z + h1.z) + (h2.z + h3.z), dv, bb1.z), 0.f);
        rb.w = fmaxf(fmaf((h0.w + h1.w) + (h2.w + h3.w), dv, bb1.w), 0.f);
        int nd = threadIdx.x >> 3;
        ((float4*)rowsS)[nd * 16 + feat8 * 2] = ra;
        ((float4*)rowsS)[nd * 16 + feat8 * 2 + 1] = rb;
    }
    __syncthreads();
    // Phase B: 32 nodes x 32 cols = 1024 outputs, 4 per thread.
#pragma unroll
    for (int rep = 0; rep < 4; ++rep) {
        int idx = rep * TB + threadIdx.x;
        int nd = idx >> 5, c = idx & 31;
        int gn = r0 + nd;
        if (gn < n) {
            const float* x = rowsS + nd * 64;
            float acc = 0.f;
#pragma unroll
            for (int k = 0; k < 64; ++k) acc = fmaf(x[k], W2s[k * 32 + c], acc);
            h2b[(size_t)gn * 32 + c] = f2bf(acc * dinv[gn]);
        }
    }
}

// ---- fused conv2-agg + FC ------------------------------------------------
// Phase A: 64 nodes/block, 8 lanes/node, bf16 uint2 gathers -> rows into LDS.
// Phase B: register-blocked FC, 2 adjacent cols/thread, f32x2 packed fma
//          (v_pk_fma_f32), f32x2 nt stores.
__global__ __launch_bounds__(FCTB, 4)
void k_aggfc(const uint2* __restrict__ H2, const int* __restrict__ off,
             const int* __restrict__ eSrc, const float* __restrict__ dinv,
             const float4* __restrict__ b4, const float* __restrict__ Wfc,
             const float* __restrict__ bfc, float* __restrict__ Y, int n) {
    __shared__ float Xs[64 * 32];  // 8KB
    int r0 = blockIdx.x * 64;
    int c0 = threadIdx.x * 2;

    f32x2 w[32];
#pragma unroll
    for (int k = 0; k < 32; ++k) w[k] = *(const f32x2*)(Wfc + k * 1024 + c0);
    f32x2 bb = *(const f32x2*)(bfc + c0);

    // ---- phase A ----
    int node = r0 + (threadIdx.x >> 3);
    int feat4 = threadIdx.x & 7;
    if (node < n) {
        int j0 = off[node], j1 = off[node + 1];
        float4 a0 = make_float4(0.f, 0.f, 0.f, 0.f);
        float4 a1 = make_float4(0.f, 0.f, 0.f, 0.f);
        float4 a2 = make_float4(0.f, 0.f, 0.f, 0.f);
        float4 a3 = make_float4(0.f, 0.f, 0.f, 0.f);
        int e = j0;
        for (; e + 4 <= j1; e += 4) {
            int s0 = eSrc[e], s1 = eSrc[e + 1], s2 = eSrc[e + 2], s3 = eSrc[e + 3];
            bf4_accum(H2[(size_t)s0 * 8 + feat4], a0);
            bf4_accum(H2[(size_t)s1 * 8 + feat4], a1);
            bf4_accum(H2[(size_t)s2 * 8 + feat4], a2);
            bf4_accum(H2[(size_t)s3 * 8 + feat4], a3);
        }
        for (; e < j1; ++e) bf4_accum(H2[(size_t)eSrc[e] * 8 + feat4], a0);
        float4 self = make_float4(0.f, 0.f, 0.f, 0.f);
        bf4_accum(H2[(size_t)node * 8 + feat4], self);
        float dv = dinv[node];
        float4 cb = b4[feat4];
        float4 r;
        r.x = fmaf((a0.x + a1.x) + (a2.x + a3.x) + self.x, dv, cb.x);
        r.y = fmaf((a0.y + a1.y) + (a2.y + a3.y) + self.y, dv, cb.y);
        r.z = fmaf((a0.z + a1.z) + (a2.z + a3.z) + self.z, dv, cb.z);
        r.w = fmaf((a0.w + a1.w) + (a2.w + a3.w) + self.w, dv, cb.w);
        ((float4*)Xs)[(threadIdx.x >> 3) * 8 + feat4] = r;
    }
    __syncthreads();

    // ---- phase B ----
    int rows = min(64, n - r0);
    for (int r = 0; r < rows; ++r) {
        const float* x = Xs + r * 32;
        f32x2 acc = bb;
#pragma unroll
        for (int k = 0; k < 32; ++k) {
            float xv = x[k];
            f32x2 xv2;
            xv2.x = xv; xv2.y = xv;
            acc = __builtin_elementwise_fma(xv2, w[k], acc);
        }
        __builtin_nontemporal_store(acc, (f32x2*)(Y + (size_t)(r0 + r) * 1024 + c0));
    }
}

// ---- launch -------------------------------------------------------------

extern "C" void kernel_launch(void* const* d_in, const int* in_sizes, int n_in,
                              void* d_out, int out_size, void* d_ws, size_t ws_size,
                              hipStream_t stream) {
    const float* z   = (const float*)d_in[0];
    const int*   ei  = (const int*)d_in[1];
    const float* W1  = (const float*)d_in[2];
    const float* b1  = (const float*)d_in[3];
    const float* W2  = (const float*)d_in[4];
    const float* b2  = (const float*)d_in[5];
    const float* Wfc = (const float*)d_in[6];
    const float* bfc = (const float*)d_in[7];
    float* out = (float*)d_out;

    int n = in_sizes[0] / 64;
    int E = in_sizes[1] / 2;
    const int* src = ei;
    const int* dst = ei + E;

    // Workspace (4-byte words):
    //   cnt[nPad] | work[16] | off[n+1 pad4] | slot[Epad] | eSrc[Epad] | dinv[nPad]
    //   | h1b (n*64 bf16 = n*32 words) | h2b (n*32 bf16 = n*16 words)
    int nPad = (n + 3) & ~3;
    int ePad = (E + 3) & ~3;
    int* cnt    = (int*)d_ws;
    int* work   = cnt + nPad;
    int* off    = work + 16;
    int* slot   = off + ((n + 1 + 3) & ~3);
    int* eSrc   = slot + ePad;
    float* dinv = (float*)(eSrc + ePad);
    unsigned short* h1b = (unsigned short*)(dinv + nPad);           // n*64 bf16
    unsigned short* h2b = (unsigned short*)(dinv + nPad + (size_t)n * 32);  // n*32 bf16

    int nChunks = (n + SCHUNK - 1) / SCHUNK;

    // ---- CSR build + norms ----
    {
        int n4 = (nPad + 16) / 4;  // zero cnt + work together
        k_zero<<<(n4 + TB - 1) / TB, TB, 0, stream>>>((int4*)cnt, n4);
    }
    k_hist<<<(E + TB - 1) / TB, TB, 0, stream>>>(dst, cnt, slot, E);
    k_scanLB<<<nChunks, 1024, 0, stream>>>(cnt, off, dinv, work, n, E);

    // ---- union: CSR fill + conv1 GEMM (bf16 out) ----
    {
        int fillBlocks = (E + TB - 1) / TB;
        int gemmBlocks = (n + 15) / 16;
        k_fill_gemm<<<fillBlocks + gemmBlocks, TB, 0, stream>>>(
            src, dst, off, slot, eSrc, E, fillBlocks, z, W1, dinv, h1b, n);
    }

    // ---- conv1 agg + conv2 GEMM -> h2b ----
    k_agg64g2<<<(n + 31) / 32, TB, 0, stream>>>((const uint4*)h1b, off, eSrc, dinv,
                                                (const float4*)b1, W2, h2b, n);

    // ---- conv2 agg + FC -> out ----
    k_aggfc<<<(n + 63) / 64, FCTB, 0, stream>>>((const uint2*)h2b, off, eSrc, dinv,
                                                (const float4*)b2, Wfc, bfc, out, n);
}

// Round 16
// 183.593 us; speedup vs baseline: 1.0153x; 1.0153x over previous
//
#include <hip/hip_runtime.h>

// GCN decoder: 2x GCNConv (self-loops, symmetric norm) + FC to 1024.
// n = 50000 nodes, E = 800000 directed edges, feats 64 -> 64 -> 32 -> 1024.
// Round 16: round-14 geometry restored (agg64g2 back to 16 nodes/block,
//           uint2 gathers); keep only round-15's packed-fma FC inner loop.

#define TB 256
#define FCTB 512
#define SCHUNK 4096        // scan elements per block (1024 thr x 4)
#define FLAGB (1 << 30)    // scan "total published" flag bit

typedef __attribute__((ext_vector_type(2))) float f32x2;

// f32 -> bf16 round-to-nearest-even
__device__ __forceinline__ unsigned short f2bf(float f) {
    unsigned u = __float_as_uint(f);
    u += 0x7fffu + ((u >> 16) & 1u);
    return (unsigned short)(u >> 16);
}

// accumulate 4 bf16 (packed uint2) into float4 (widening exact)
__device__ __forceinline__ void bf4_accum(uint2 p, float4& a) {
    a.x += __uint_as_float(p.x << 16);
    a.y += __uint_as_float(p.x & 0xffff0000u);
    a.z += __uint_as_float(p.y << 16);
    a.w += __uint_as_float(p.y & 0xffff0000u);
}

// ---- utility ------------------------------------------------------------

__global__ void k_zero(int4* __restrict__ p, int n4) {
    int i = blockIdx.x * TB + threadIdx.x;
    if (i < n4) p[i] = make_int4(0, 0, 0, 0);
}

// ---- CSR build ----------------------------------------------------------

__global__ void k_hist(const int* __restrict__ dst, int* __restrict__ cnt,
                       int* __restrict__ slot, int E) {
    int e = blockIdx.x * TB + threadIdx.x;
    if (e < E) slot[e] = atomicAdd(&cnt[dst[e]], 1);
}

// Exclusive scan cnt -> off (+ fused dinv); decoupled lookback (<=13 blocks).
__global__ __launch_bounds__(1024)
void k_scanLB(const int* __restrict__ cnt, int* __restrict__ off,
              float* __restrict__ dinv, int* __restrict__ work, int n, int E) {
    __shared__ int wsum[16];
    __shared__ int pfx_s;
    int b = blockIdx.x;
    int i4 = b * SCHUNK + threadIdx.x * 4;
    int lane = threadIdx.x & 63, wid = threadIdx.x >> 6;
    int v0 = 0, v1 = 0, v2 = 0, v3 = 0;
    if (i4 + 3 < n) {
        int4 t = *(const int4*)(cnt + i4);
        v0 = t.x; v1 = t.y; v2 = t.z; v3 = t.w;
    } else {
        if (i4 < n) v0 = cnt[i4];
        if (i4 + 1 < n) v1 = cnt[i4 + 1];
        if (i4 + 2 < n) v2 = cnt[i4 + 2];
        if (i4 + 3 < n) v3 = cnt[i4 + 3];
    }
    if (i4 < n)     dinv[i4]     = rsqrtf((float)(v0 + 1));
    if (i4 + 1 < n) dinv[i4 + 1] = rsqrtf((float)(v1 + 1));
    if (i4 + 2 < n) dinv[i4 + 2] = rsqrtf((float)(v2 + 1));
    if (i4 + 3 < n) dinv[i4 + 3] = rsqrtf((float)(v3 + 1));

    int s = v0 + v1 + v2 + v3;
    int x = s;
#pragma unroll
    for (int ofs = 1; ofs < 64; ofs <<= 1) {
        int t = __shfl_up(x, ofs, 64);
        if (lane >= ofs) x += t;
    }
    if (lane == 63) wsum[wid] = x;
    __syncthreads();
    int wp = 0;
#pragma unroll
    for (int wv = 0; wv < 16; ++wv) wp += (wv < wid) ? wsum[wv] : 0;
    int excl = wp + x - s;

    if (threadIdx.x == 0) {
        int tot = 0;
#pragma unroll
        for (int wv = 0; wv < 16; ++wv) tot += wsum[wv];
        atomicOr(&work[b], tot | FLAGB);
        int pfx = 0;
        for (int j = 0; j < b; ++j) {
            int v;
            do { v = atomicOr(&work[j], 0); } while (!(v & FLAGB));
            pfx += v & (FLAGB - 1);
        }
        pfx_s = pfx;
        if (b == 0) off[n] = E;
    }
    __syncthreads();
    excl += pfx_s;
    if (i4 < n)     off[i4]     = excl;
    if (i4 + 1 < n) off[i4 + 1] = excl + v0;
    if (i4 + 2 < n) off[i4 + 2] = excl + v0 + v1;
    if (i4 + 3 < n) off[i4 + 3] = excl + v0 + v1 + v2;
}

// ---- union dispatch: CSR fill + conv1 GEMM (bf16 out) --------------------
__global__ void k_fill_gemm(const int* __restrict__ src, const int* __restrict__ dst,
                            const int* __restrict__ off, const int* __restrict__ slot,
                            int* __restrict__ eSrc, int E, int fillBlocks,
                            const float* __restrict__ X, const float* __restrict__ W,
                            const float* __restrict__ dinv,
                            unsigned short* __restrict__ Y, int n) {
    __shared__ float Ws[64 * 64];
    __shared__ float Xs[16 * 64];
    if ((int)blockIdx.x < fillBlocks) {
        int e = blockIdx.x * TB + threadIdx.x;
        if (e < E) eSrc[off[dst[e]] + slot[e]] = src[e];
        return;
    }
    int gb = blockIdx.x - fillBlocks;
    for (int i = threadIdx.x; i < 64 * 64; i += TB) Ws[i] = W[i];
    int r0 = gb * 16;
    int rows = min(16, n - r0);
    {
        const float4* Xg = (const float4*)(X + (size_t)r0 * 64);
        float4* Xs4 = (float4*)Xs;
        int tot4 = rows * 16;
        for (int i = threadIdx.x; i < tot4; i += TB) Xs4[i] = Xg[i];
    }
    __syncthreads();
    int c = threadIdx.x & 63;
    int g = threadIdx.x >> 6;  // 0..3
#pragma unroll
    for (int rr = 0; rr < 4; ++rr) {
        int rb = g + rr * 4;
        int r = r0 + rb;
        if (r >= n) break;
        const float* x = Xs + rb * 64;
        float acc = 0.f;
#pragma unroll
        for (int k = 0; k < 64; ++k) acc = fmaf(x[k], Ws[k * 64 + c], acc);
        Y[(size_t)r * 64 + c] = f2bf(acc * dinv[r]);
    }
}

// ---- fused conv1-agg + conv2-GEMM (round-14 geometry) --------------------
// Phase A: 16 nodes/block, 16 lanes/node, bf16 uint2 gathers, 4-way unroll
//          -> post-relu rows into LDS.
// Phase B: h2b[nd,c] = bf16( dinv[nd] * rows[nd] @ W2[:,c] ), W2 in LDS.
__global__ void k_agg64g2(const uint2* __restrict__ H2, const int* __restrict__ off,
                          const int* __restrict__ eSrc, const float* __restrict__ dinv,
                          const float4* __restrict__ b4, const float* __restrict__ W2,
                          unsigned short* __restrict__ h2b, int n) {
    __shared__ float rowsS[16 * 64];  // 4KB
    __shared__ float W2s[64 * 32];    // 8KB
    for (int i = threadIdx.x; i < 64 * 32; i += TB) W2s[i] = W2[i];
    int r0 = blockIdx.x * 16;
    int node = r0 + (threadIdx.x >> 4);
    int feat4 = threadIdx.x & 15;
    if (node < n) {
        int j0 = off[node], j1 = off[node + 1];
        float4 a0 = make_float4(0.f, 0.f, 0.f, 0.f);
        float4 a1 = make_float4(0.f, 0.f, 0.f, 0.f);
        float4 a2 = make_float4(0.f, 0.f, 0.f, 0.f);
        float4 a3 = make_float4(0.f, 0.f, 0.f, 0.f);
        int e = j0;
        for (; e + 4 <= j1; e += 4) {
            int s0 = eSrc[e], s1 = eSrc[e + 1], s2 = eSrc[e + 2], s3 = eSrc[e + 3];
            bf4_accum(H2[(size_t)s0 * 16 + feat4], a0);
            bf4_accum(H2[(size_t)s1 * 16 + feat4], a1);
            bf4_accum(H2[(size_t)s2 * 16 + feat4], a2);
            bf4_accum(H2[(size_t)s3 * 16 + feat4], a3);
        }
        for (; e < j1; ++e) bf4_accum(H2[(size_t)eSrc[e] * 16 + feat4], a0);
        float4 self = make_float4(0.f, 0.f, 0.f, 0.f);
        bf4_accum(H2[(size_t)node * 16 + feat4], self);
        float dv = dinv[node];
        float4 bb = b4[feat4];
        float4 r;
        r.x = fmaxf(fmaf((a0.x + a1.x) + (a2.x + a3.x) + self.x, dv, bb.x), 0.f);
        r.y = fmaxf(fmaf((a0.y + a1.y) + (a2.y + a3.y) + self.y, dv, bb.y), 0.f);
        r.z = fmaxf(fmaf((a0.z + a1.z) + (a2.z + a3.z) + self.z, dv, bb.z), 0.f);
        r.w = fmaxf(fmaf((a0.w + a1.w) + (a2.w + a3.w) + self.w, dv, bb.w), 0.f);
        ((float4*)rowsS)[(threadIdx.x >> 4) * 16 + feat4] = r;
    }
    __syncthreads();
    // Phase B: 16 nodes x 32 cols = 512 outputs, 2 per thread.
#pragma unroll
    for (int rep = 0; rep < 2; ++rep) {
        int idx = rep * TB + threadIdx.x;
        int nd = idx >> 5, c = idx & 31;
        int gn = r0 + nd;
        if (gn < n) {
            const float* x = rowsS + nd * 64;
            float acc = 0.f;
#pragma unroll
            for (int k = 0; k < 64; ++k) acc = fmaf(x[k], W2s[k * 32 + c], acc);
            h2b[(size_t)gn * 32 + c] = f2bf(acc * dinv[gn]);
        }
    }
}

// ---- fused conv2-agg + FC ------------------------------------------------
// Phase A: 64 nodes/block, 8 lanes/node, bf16 uint2 gathers -> rows into LDS.
// Phase B: register-blocked FC, 2 adjacent cols/thread, f32x2 packed fma
//          (v_pk_fma_f32), f32x2 nt stores.
__global__ __launch_bounds__(FCTB, 4)
void k_aggfc(const uint2* __restrict__ H2, const int* __restrict__ off,
             const int* __restrict__ eSrc, const float* __restrict__ dinv,
             const float4* __restrict__ b4, const float* __restrict__ Wfc,
             const float* __restrict__ bfc, float* __restrict__ Y, int n) {
    __shared__ float Xs[64 * 32];  // 8KB
    int r0 = blockIdx.x * 64;
    int c0 = threadIdx.x * 2;

    f32x2 w[32];
#pragma unroll
    for (int k = 0; k < 32; ++k) w[k] = *(const f32x2*)(Wfc + k * 1024 + c0);
    f32x2 bb = *(const f32x2*)(bfc + c0);

    // ---- phase A ----
    int node = r0 + (threadIdx.x >> 3);
    int feat4 = threadIdx.x & 7;
    if (node < n) {
        int j0 = off[node], j1 = off[node + 1];
        float4 a0 = make_float4(0.f, 0.f, 0.f, 0.f);
        float4 a1 = make_float4(0.f, 0.f, 0.f, 0.f);
        float4 a2 = make_float4(0.f, 0.f, 0.f, 0.f);
        float4 a3 = make_float4(0.f, 0.f, 0.f, 0.f);
        int e = j0;
        for (; e + 4 <= j1; e += 4) {
            int s0 = eSrc[e], s1 = eSrc[e + 1], s2 = eSrc[e + 2], s3 = eSrc[e + 3];
            bf4_accum(H2[(size_t)s0 * 8 + feat4], a0);
            bf4_accum(H2[(size_t)s1 * 8 + feat4], a1);
            bf4_accum(H2[(size_t)s2 * 8 + feat4], a2);
            bf4_accum(H2[(size_t)s3 * 8 + feat4], a3);
        }
        for (; e < j1; ++e) bf4_accum(H2[(size_t)eSrc[e] * 8 + feat4], a0);
        float4 self = make_float4(0.f, 0.f, 0.f, 0.f);
        bf4_accum(H2[(size_t)node * 8 + feat4], self);
        float dv = dinv[node];
        float4 cb = b4[feat4];
        float4 r;
        r.x = fmaf((a0.x + a1.x) + (a2.x + a3.x) + self.x, dv, cb.x);
        r.y = fmaf((a0.y + a1.y) + (a2.y + a3.y) + self.y, dv, cb.y);
        r.z = fmaf((a0.z + a1.z) + (a2.z + a3.z) + self.z, dv, cb.z);
        r.w = fmaf((a0.w + a1.w) + (a2.w + a3.w) + self.w, dv, cb.w);
        ((float4*)Xs)[(threadIdx.x >> 3) * 8 + feat4] = r;
    }
    __syncthreads();

    // ---- phase B ----
    int rows = min(64, n - r0);
    for (int r = 0; r < rows; ++r) {
        const float* x = Xs + r * 32;
        f32x2 acc = bb;
#pragma unroll
        for (int k = 0; k < 32; ++k) {
            float xv = x[k];
            f32x2 xv2;
            xv2.x = xv; xv2.y = xv;
            acc = __builtin_elementwise_fma(xv2, w[k], acc);
        }
        __builtin_nontemporal_store(acc, (f32x2*)(Y + (size_t)(r0 + r) * 1024 + c0));
    }
}

// ---- launch -------------------------------------------------------------

extern "C" void kernel_launch(void* const* d_in, const int* in_sizes, int n_in,
                              void* d_out, int out_size, void* d_ws, size_t ws_size,
                              hipStream_t stream) {
    const float* z   = (const float*)d_in[0];
    const int*   ei  = (const int*)d_in[1];
    const float* W1  = (const float*)d_in[2];
    const float* b1  = (const float*)d_in[3];
    const float* W2  = (const float*)d_in[4];
    const float* b2  = (const float*)d_in[5];
    const float* Wfc = (const float*)d_in[6];
    const float* bfc = (const float*)d_in[7];
    float* out = (float*)d_out;

    int n = in_sizes[0] / 64;
    int E = in_sizes[1] / 2;
    const int* src = ei;
    const int* dst = ei + E;

    // Workspace (4-byte words):
    //   cnt[nPad] | work[16] | off[n+1 pad4] | slot[Epad] | eSrc[Epad] | dinv[nPad]
    //   | h1b (n*64 bf16 = n*32 words) | h2b (n*32 bf16 = n*16 words)
    int nPad = (n + 3) & ~3;
    int ePad = (E + 3) & ~3;
    int* cnt    = (int*)d_ws;
    int* work   = cnt + nPad;
    int* off    = work + 16;
    int* slot   = off + ((n + 1 + 3) & ~3);
    int* eSrc   = slot + ePad;
    float* dinv = (float*)(eSrc + ePad);
    unsigned short* h1b = (unsigned short*)(dinv + nPad);           // n*64 bf16
    unsigned short* h2b = (unsigned short*)(dinv + nPad + (size_t)n * 32);  // n*32 bf16

    int nChunks = (n + SCHUNK - 1) / SCHUNK;

    // ---- CSR build + norms ----
    {
        int n4 = (nPad + 16) / 4;  // zero cnt + work together
        k_zero<<<(n4 + TB - 1) / TB, TB, 0, stream>>>((int4*)cnt, n4);
    }
    k_hist<<<(E + TB - 1) / TB, TB, 0, stream>>>(dst, cnt, slot, E);
    k_scanLB<<<nChunks, 1024, 0, stream>>>(cnt, off, dinv, work, n, E);

    // ---- union: CSR fill + conv1 GEMM (bf16 out) ----
    {
        int fillBlocks = (E + TB - 1) / TB;
        int gemmBlocks = (n + 15) / 16;
        k_fill_gemm<<<fillBlocks + gemmBlocks, TB, 0, stream>>>(
            src, dst, off, slot, eSrc, E, fillBlocks, z, W1, dinv, h1b, n);
    }

    // ---- conv1 agg + conv2 GEMM -> h2b ----
    k_agg64g2<<<(n + 15) / 16, TB, 0, stream>>>((const uint2*)h1b, off, eSrc, dinv,
                                                (const float4*)b1, W2, h2b, n);

    // ---- conv2 agg + FC -> out ----
    k_aggfc<<<(n + 63) / 64, FCTB, 0, stream>>>((const uint2*)h2b, off, eSrc, dinv,
                                                (const float4*)b2, Wfc, bfc, out, n);
}